// Round 4
// baseline (8448.313 us; speedup 1.0000x reference)
//
#include <hip/hip_runtime.h>
#include <hip/hip_bf16.h>
#include <math.h>

typedef __bf16 bf16_t;
typedef __bf16 bf16x8 __attribute__((ext_vector_type(8)));
typedef float  f32x4  __attribute__((ext_vector_type(4)));

#define TOKENS 8192
#define DIMV   768
#define INNERV 768
#define QKVW   2304
#define MLPW   3072
#define NSEQ   1024
#define NB     8
#define NH     12
#define DH     64

enum { EP_STORE = 0, EP_BIAS_RES = 1, EP_BIAS_GELU = 2 };

// ---------------- GEMM: C[M,N] = s * (A[M,K] * B[N,K]^T) + bias, bf16 in, f32 acc ----
// 256 threads = 4 waves (2x2), 128x128 tile, BK=32, mfma_f32_16x16x32_bf16.
// B holds EXACT ternary {-1,0,1} (or plain bf16 weights); scale s = (*sacc)*sinvn+sbias
// applied in f32 epilogue so weight quantization adds no extra rounding error.
__global__ __launch_bounds__(256)
void gemm_nt(const bf16_t* __restrict__ A, const bf16_t* __restrict__ B,
             const int K, const int N, const int mode,
             const float* __restrict__ sacc_p, const float sinvn, const float sbias,
             const float* __restrict__ bias,
             float* __restrict__ resid,
             bf16_t* __restrict__ outb)
{
  __shared__ __align__(16) bf16_t lsA[128 * 32];
  __shared__ __align__(16) bf16_t lsB[128 * 32];
  const int tid  = threadIdx.x;
  const int lane = tid & 63;
  const int wave = tid >> 6;
  const int wm = wave >> 1, wn = wave & 1;
  const int bm = blockIdx.x, bn = blockIdx.y;

  const int sr = tid >> 2;           // staging row 0..63 (and +64)
  const int sc = (tid & 3) * 8;      // staging col 0,8,16,24
  const bf16_t* gA = A + (size_t)(bm * 128 + sr) * K + sc;
  const bf16_t* gB = B + (size_t)(bn * 128 + sr) * K + sc;

  f32x4 acc[4][4];
#pragma unroll
  for (int i = 0; i < 4; i++)
#pragma unroll
    for (int j = 0; j < 4; j++) acc[i][j] = (f32x4){0.f, 0.f, 0.f, 0.f};

  // A/B fragment: elem[m=lane&15][k=(lane>>4)*8+j]
  const int arow = (wm * 64 + (lane & 15)) * 32 + (lane >> 4) * 8;
  const int brow = (wn * 64 + (lane & 15)) * 32 + (lane >> 4) * 8;

  for (int kb = 0; kb < K; kb += 32) {
    bf16x8 a0 = *(const bf16x8*)(gA + kb);
    bf16x8 a1 = *(const bf16x8*)(gA + (size_t)64 * K + kb);
    bf16x8 b0 = *(const bf16x8*)(gB + kb);
    bf16x8 b1 = *(const bf16x8*)(gB + (size_t)64 * K + kb);
    __syncthreads();
    *(bf16x8*)&lsA[sr * 32 + sc]        = a0;
    *(bf16x8*)&lsA[(64 + sr) * 32 + sc] = a1;
    *(bf16x8*)&lsB[sr * 32 + sc]        = b0;
    *(bf16x8*)&lsB[(64 + sr) * 32 + sc] = b1;
    __syncthreads();
    bf16x8 af[4], bfv[4];
#pragma unroll
    for (int i = 0; i < 4; i++) af[i]  = *(const bf16x8*)&lsA[arow + i * 16 * 32];
#pragma unroll
    for (int j = 0; j < 4; j++) bfv[j] = *(const bf16x8*)&lsB[brow + j * 16 * 32];
#pragma unroll
    for (int i = 0; i < 4; i++)
#pragma unroll
      for (int j = 0; j < 4; j++)
        acc[i][j] = __builtin_amdgcn_mfma_f32_16x16x32_bf16(af[i], bfv[j], acc[i][j], 0, 0, 0);
  }

  const float s = (*sacc_p) * sinvn + sbias;
  // C/D layout: col = lane&15, row = (lane>>4)*4 + reg
  const int r0 = bm * 128 + wm * 64 + (lane >> 4) * 4;
  const int c0 = bn * 128 + wn * 64 + (lane & 15);
#pragma unroll
  for (int i = 0; i < 4; i++) {
#pragma unroll
    for (int j = 0; j < 4; j++) {
      const int col = c0 + j * 16;
#pragma unroll
      for (int r = 0; r < 4; r++) {
        const int row = r0 + i * 16 + r;
        const float v = acc[i][j][r] * s;
        const size_t idx = (size_t)row * N + col;
        if (mode == EP_STORE) {
          outb[idx] = (bf16_t)v;
        } else if (mode == EP_BIAS_RES) {
          resid[idx] += v + bias[col];
        } else {  // EP_BIAS_GELU (exact gelu)
          const float t = v + bias[col];
          outb[idx] = (bf16_t)(0.5f * t * (1.0f + erff(t * 0.70710678118654752f)));
        }
      }
    }
  }
}

// ---------------- LayerNorm: one block per row; f32 gamma/beta; bf16 out -------------
template <typename TIN>
__global__ __launch_bounds__(256)
void ln_kern(const TIN* __restrict__ x, const float* __restrict__ g,
             const float* __restrict__ b, bf16_t* __restrict__ y, const int W)
{
  const int row = blockIdx.x;
  const int tid = threadIdx.x;
  const TIN* xr = x + (size_t)row * W;
  float s = 0.f, s2 = 0.f;
  for (int i = tid; i < W; i += 256) {
    const float v = (float)xr[i];
    s += v; s2 += v * v;
  }
#pragma unroll
  for (int off = 32; off > 0; off >>= 1) {
    s  += __shfl_xor(s,  off, 64);
    s2 += __shfl_xor(s2, off, 64);
  }
  __shared__ float red[8];
  if ((tid & 63) == 0) { red[(tid >> 6) * 2] = s; red[(tid >> 6) * 2 + 1] = s2; }
  __syncthreads();
  const float ts  = red[0] + red[2] + red[4] + red[6];
  const float ts2 = red[1] + red[3] + red[5] + red[7];
  const float invW = 1.0f / (float)W;
  const float mean = ts * invW;
  const float var  = fmaxf(ts2 * invW - mean * mean, 0.f);
  const float rs   = rsqrtf(var + 1e-5f);
  bf16_t* yr = y + (size_t)row * W;
  for (int i = tid; i < W; i += 256) {
    const float v = ((float)xr[i] - mean) * rs * g[i] + b[i];
    yr[i] = (bf16_t)v;
  }
}

// ---------------- Flash attention (VALU, f32). 128 q-rows per WG, 64-row KV tiles ----
__global__ __launch_bounds__(128)
void attn_kern(const bf16_t* __restrict__ qkv, bf16_t* __restrict__ o)
{
  __shared__ __align__(16) float Ks[64][68];
  __shared__ __align__(16) float Vs[64][68];
  __shared__ bf16_t Ss[128][66];
  const int tid = threadIdx.x;
  const int qc = blockIdx.x, hh = blockIdx.y, bb = blockIdx.z;
  const int n = qc * 128 + tid;
  const size_t tokbase = (size_t)bb * NSEQ;

  const bf16_t* qp = qkv + (tokbase + n) * QKVW + hh * DH;
  f32x4 qv[16], ov[16];
#pragma unroll
  for (int i = 0; i < 16; i++) ov[i] = (f32x4){0.f, 0.f, 0.f, 0.f};
#pragma unroll
  for (int i = 0; i < 8; i++) {
    bf16x8 t = *(const bf16x8*)(qp + i * 8);
#pragma unroll
    for (int e = 0; e < 8; e++) ((float*)qv)[i * 8 + e] = (float)t[e] * 0.125f;  // fold 1/sqrt(64)
  }
  float m = -1e30f, l = 0.f;

  for (int kt = 0; kt < NSEQ / 64; ++kt) {
    __syncthreads();
    {
      const int r = tid >> 1, dbase = (tid & 1) * 32;
      const bf16_t* kp = qkv + (tokbase + kt * 64 + r) * QKVW + INNERV + hh * DH + dbase;
      const bf16_t* vp = kp + INNERV;
#pragma unroll
      for (int i = 0; i < 4; i++) {
        bf16x8 t = *(const bf16x8*)(kp + i * 8);
        f32x4 lo = {(float)t[0], (float)t[1], (float)t[2], (float)t[3]};
        f32x4 hi = {(float)t[4], (float)t[5], (float)t[6], (float)t[7]};
        *(f32x4*)&Ks[r][dbase + i * 8]     = lo;
        *(f32x4*)&Ks[r][dbase + i * 8 + 4] = hi;
      }
#pragma unroll
      for (int i = 0; i < 4; i++) {
        bf16x8 t = *(const bf16x8*)(vp + i * 8);
        f32x4 lo = {(float)t[0], (float)t[1], (float)t[2], (float)t[3]};
        f32x4 hi = {(float)t[4], (float)t[5], (float)t[6], (float)t[7]};
        *(f32x4*)&Vs[r][dbase + i * 8]     = lo;
        *(f32x4*)&Vs[r][dbase + i * 8 + 4] = hi;
      }
    }
    __syncthreads();
    float tmax = -1e30f;
    for (int j = 0; j < 64; ++j) {
      const f32x4* kr = (const f32x4*)&Ks[j][0];
      f32x4 sa = (f32x4){0.f, 0.f, 0.f, 0.f};
#pragma unroll
      for (int d = 0; d < 16; ++d) sa += qv[d] * kr[d];
      const float sj = sa[0] + sa[1] + sa[2] + sa[3];
      Ss[tid][j] = (bf16_t)sj;
      tmax = fmaxf(tmax, sj);
    }
    const float mnew = fmaxf(m, tmax);
    const float alpha = __expf(m - mnew);
    l *= alpha;
#pragma unroll
    for (int d = 0; d < 16; ++d) ov[d] *= alpha;
    for (int j = 0; j < 64; ++j) {
      const float p = __expf((float)Ss[tid][j] - mnew);
      l += p;
      const f32x4* vr = (const f32x4*)&Vs[j][0];
#pragma unroll
      for (int d = 0; d < 16; ++d) ov[d] += p * vr[d];
    }
    m = mnew;
  }
  const float inv = 1.0f / l;
  bf16_t* op = o + (tokbase + n) * INNERV + hh * DH;
#pragma unroll
  for (int i = 0; i < 16; i++)
#pragma unroll
    for (int e = 0; e < 4; e++) op[i * 4 + e] = (bf16_t)(ov[i][e] * inv);
}

// ---------------- ternary quant helpers (f32 weights in) ----------------
__global__ __launch_bounds__(64)
void zero_kern(float* __restrict__ p)
{
  p[threadIdx.x] = 0.f;
}

__global__ __launch_bounds__(256)
void absmean_kern(const float* __restrict__ w, const long n, float* __restrict__ acc)
{
  const int tid = threadIdx.x;
  float s = 0.f;
  const size_t stride = (size_t)256 * gridDim.x * 4;
  for (size_t i = ((size_t)blockIdx.x * 256 + tid) * 4; i < (size_t)n; i += stride) {
    f32x4 t = *(const f32x4*)(w + i);
    s += fabsf(t[0]) + fabsf(t[1]) + fabsf(t[2]) + fabsf(t[3]);
  }
#pragma unroll
  for (int off = 32; off > 0; off >>= 1) s += __shfl_xor(s, off, 64);
  __shared__ float red[4];
  if ((tid & 63) == 0) red[tid >> 6] = s;
  __syncthreads();
  if (tid == 0) atomicAdd(acc, red[0] + red[1] + red[2] + red[3]);
}

// ternary: wq = clip(round(w/s), -1, 1) stored EXACTLY as bf16 {-1,0,1}; s applied in GEMM
__global__ __launch_bounds__(256)
void quant_kern(const float* __restrict__ w, bf16_t* __restrict__ wq,
                const int n, const float* __restrict__ acc, const float invn)
{
  const int i = blockIdx.x * 256 + threadIdx.x;
  if (i >= n) return;
  const float s = (*acc) * invn + 1e-8f;
  float q = rintf(w[i] / s);  // round-half-even, matches jnp.round
  q = fminf(1.f, fmaxf(-1.f, q));
  wq[i] = (bf16_t)q;
}

__global__ __launch_bounds__(256)
void copyf_kern(const float* __restrict__ in, float* __restrict__ out, const int n4)
{
  const int i = blockIdx.x * 256 + threadIdx.x;
  if (i < n4) ((f32x4*)out)[i] = ((const f32x4*)in)[i];
}

__global__ __launch_bounds__(256)
void f2b_kern(const float* __restrict__ in, bf16_t* __restrict__ out, const int n)
{
  const int i = blockIdx.x * 256 + threadIdx.x;
  if (i < n) out[i] = (bf16_t)in[i];
}

// ---------------- driver ----------------
extern "C" void kernel_launch(void* const* d_in, const int* in_sizes, int n_in,
                              void* d_out, int out_size, void* d_ws, size_t ws_size,
                              hipStream_t stream)
{
  // ALL inputs are float32 (per reference setup_inputs dtypes).
  const float* x     = (const float*)d_in[0];
  const float* ln1_g = (const float*)d_in[1];
  const float* ln1_b = (const float*)d_in[2];
  const float* Wqkv  = (const float*)d_in[3];
  const float* ln2_g = (const float*)d_in[4];
  const float* ln2_b = (const float*)d_in[5];
  const float* Wo    = (const float*)d_in[6];
  const float* bo    = (const float*)d_in[7];
  const float* fg1   = (const float*)d_in[8];
  const float* fb1   = (const float*)d_in[9];
  const float* W1    = (const float*)d_in[10];
  const float* b1    = (const float*)d_in[11];
  const float* fg2   = (const float*)d_in[12];
  const float* fb2   = (const float*)d_in[13];
  const float* W2    = (const float*)d_in[14];
  const float* b2    = (const float*)d_in[15];

  char* ws = (char*)d_ws;
  size_t off = 0;
  float*  sacc  = (float*)(ws + off);  off += 256;                         // scale sums; [63] stays 0
  float*  h     = (float*)(ws + off);  off += (size_t)TOKENS * DIMV * 4;   // 25.2 MB residual stream
  bf16_t* bigA  = (bf16_t*)(ws + off); off += (size_t)TOKENS * MLPW * 2;   // 50.3 MB LN outs / attn out
  bf16_t* bigB  = (bf16_t*)(ws + off); off += (size_t)TOKENS * MLPW * 2;   // 50.3 MB qkv / gelu out
  bf16_t* q_qkv = (bf16_t*)(ws + off); off += (size_t)QKVW * DIMV * 2;
  bf16_t* q_o   = (bf16_t*)(ws + off); off += (size_t)DIMV * INNERV * 2;
  bf16_t* q_1   = (bf16_t*)(ws + off); off += (size_t)MLPW * DIMV * 2;
  bf16_t* q_2   = (bf16_t*)(ws + off); off += (size_t)DIMV * MLPW * 2;     // total ~140 MB

  bf16_t* obuf   = bigA;                              // attn out (12.6 MB)
  bf16_t* ln2out = bigA + (size_t)TOKENS * INNERV;    // LN2 out

  zero_kern<<<1, 64, 0, stream>>>(sacc);
  copyf_kern<<<TOKENS * DIMV / 4 / 256, 256, 0, stream>>>(x, h, TOKENS * DIMV / 4);

  for (int lyr = 0; lyr < 6; ++lyr) {
    const float* wqkv_l = Wqkv + (size_t)lyr * QKVW * DIMV;
    const float* wo_l   = Wo   + (size_t)lyr * DIMV * INNERV;
    const float* w1_l   = W1   + (size_t)lyr * MLPW * DIMV;
    const float* w2_l   = W2   + (size_t)lyr * DIMV * MLPW;
    const float *sq, *so, *s1, *s2p;
    float iq, io, i1, i2, bq, bo2, bb1v, bb2v;
    if (lyr < 5) {
      absmean_kern<<<256, 256, 0, stream>>>(wqkv_l, (long)QKVW * DIMV, &sacc[lyr * 4 + 0]);
      absmean_kern<<<256, 256, 0, stream>>>(wo_l,   (long)DIMV * INNERV, &sacc[lyr * 4 + 1]);
      absmean_kern<<<256, 256, 0, stream>>>(w1_l,   (long)MLPW * DIMV, &sacc[lyr * 4 + 2]);
      absmean_kern<<<256, 256, 0, stream>>>(w2_l,   (long)DIMV * MLPW, &sacc[lyr * 4 + 3]);
      quant_kern<<<QKVW * DIMV / 256, 256, 0, stream>>>(wqkv_l, q_qkv, QKVW * DIMV, &sacc[lyr * 4 + 0], 1.0f / (QKVW * DIMV));
      quant_kern<<<DIMV * INNERV / 256, 256, 0, stream>>>(wo_l, q_o, DIMV * INNERV, &sacc[lyr * 4 + 1], 1.0f / (DIMV * INNERV));
      quant_kern<<<MLPW * DIMV / 256, 256, 0, stream>>>(w1_l, q_1, MLPW * DIMV, &sacc[lyr * 4 + 2], 1.0f / (MLPW * DIMV));
      quant_kern<<<DIMV * MLPW / 256, 256, 0, stream>>>(w2_l, q_2, DIMV * MLPW, &sacc[lyr * 4 + 3], 1.0f / (DIMV * MLPW));
      sq = &sacc[lyr * 4 + 0]; iq = 1.0f / (QKVW * DIMV); bq = 1e-8f;
      so = &sacc[lyr * 4 + 1]; io = 1.0f / (DIMV * INNERV); bo2 = 1e-8f;
      s1 = &sacc[lyr * 4 + 2]; i1 = 1.0f / (MLPW * DIMV); bb1v = 1e-8f;
      s2p = &sacc[lyr * 4 + 3]; i2 = 1.0f / (DIMV * MLPW); bb2v = 1e-8f;
    } else {
      // last layer: plain weights, bf16-cast, scale 1.0
      f2b_kern<<<QKVW * DIMV / 256, 256, 0, stream>>>(wqkv_l, q_qkv, QKVW * DIMV);
      f2b_kern<<<DIMV * INNERV / 256, 256, 0, stream>>>(wo_l, q_o, DIMV * INNERV);
      f2b_kern<<<MLPW * DIMV / 256, 256, 0, stream>>>(w1_l, q_1, MLPW * DIMV);
      f2b_kern<<<DIMV * MLPW / 256, 256, 0, stream>>>(w2_l, q_2, DIMV * MLPW);
      sq = so = s1 = s2p = &sacc[63];  // contains 0
      iq = io = i1 = i2 = 0.f;
      bq = bo2 = bb1v = bb2v = 1.0f;   // s = 0*0 + 1 = 1
    }

    // attention sub-block
    ln_kern<float><<<TOKENS, 256, 0, stream>>>(h, ln1_g + lyr * DIMV, ln1_b + lyr * DIMV, bigA, DIMV);
    gemm_nt<<<dim3(64, QKVW / 128), 256, 0, stream>>>(bigA, q_qkv, DIMV, QKVW, EP_STORE, sq, iq, bq, nullptr, nullptr, bigB);
    attn_kern<<<dim3(NSEQ / 128, NH, NB), 128, 0, stream>>>(bigB, obuf);
    ln_kern<bf16_t><<<TOKENS, 256, 0, stream>>>(obuf, ln2_g + lyr * INNERV, ln2_b + lyr * INNERV, ln2out, INNERV);
    gemm_nt<<<dim3(64, DIMV / 128), 256, 0, stream>>>(ln2out, q_o, INNERV, DIMV, EP_BIAS_RES, so, io, bo2, bo + lyr * DIMV, h, nullptr);
    // FF sub-block
    ln_kern<float><<<TOKENS, 256, 0, stream>>>(h, fg1 + lyr * DIMV, fb1 + lyr * DIMV, bigA, DIMV);
    gemm_nt<<<dim3(64, MLPW / 128), 256, 0, stream>>>(bigA, q_1, DIMV, MLPW, EP_BIAS_GELU, s1, i1, bb1v, b1 + lyr * MLPW, nullptr, bigB);
    ln_kern<bf16_t><<<TOKENS, 256, 0, stream>>>(bigB, fg2 + lyr * MLPW, fb2 + lyr * MLPW, bigA, MLPW);
    gemm_nt<<<dim3(64, DIMV / 128), 256, 0, stream>>>(bigA, q_2, MLPW, DIMV, EP_BIAS_RES, s2p, i2, bb2v, b2 + lyr * DIMV, h, nullptr);
  }

  // OUTPUT IS FLOAT32 (reference returns f32) — copy residual stream directly.
  copyf_kern<<<TOKENS * DIMV / 4 / 256, 256, 0, stream>>>(h, (float*)d_out, TOKENS * DIMV / 4);
}

// Round 5
// 3039.620 us; speedup vs baseline: 2.7794x; 2.7794x over previous
//
#include <hip/hip_runtime.h>
#include <hip/hip_bf16.h>
#include <math.h>

typedef __bf16 bf16_t;
typedef __bf16 bf16x8 __attribute__((ext_vector_type(8)));
typedef float  f32x4  __attribute__((ext_vector_type(4)));

#define TOKENS 8192
#define DIMV   768
#define INNERV 768
#define QKVW   2304
#define MLPW   3072
#define NSEQ   1024
#define NB     8
#define NH     12
#define DH     64

enum { EP_STORE = 0, EP_BIAS_RES = 1, EP_BIAS_GELU = 2 };

// ---------------- GEMM: C[M,N] = s * (A[M,K] * B[N,K]^T) + bias, bf16 in, f32 acc ----
__global__ __launch_bounds__(256)
void gemm_nt(const bf16_t* __restrict__ A, const bf16_t* __restrict__ B,
             const int K, const int N, const int mode,
             const float* __restrict__ sacc_p, const float sinvn, const float sbias,
             const float* __restrict__ bias,
             float* __restrict__ resid,
             bf16_t* __restrict__ outb)
{
  __shared__ __align__(16) bf16_t lsA[128 * 32];
  __shared__ __align__(16) bf16_t lsB[128 * 32];
  const int tid  = threadIdx.x;
  const int lane = tid & 63;
  const int wave = tid >> 6;
  const int wm = wave >> 1, wn = wave & 1;
  const int bm = blockIdx.x, bn = blockIdx.y;

  const int sr = tid >> 2;
  const int sc = (tid & 3) * 8;
  const bf16_t* gA = A + (size_t)(bm * 128 + sr) * K + sc;
  const bf16_t* gB = B + (size_t)(bn * 128 + sr) * K + sc;

  f32x4 acc[4][4];
#pragma unroll
  for (int i = 0; i < 4; i++)
#pragma unroll
    for (int j = 0; j < 4; j++) acc[i][j] = (f32x4){0.f, 0.f, 0.f, 0.f};

  const int arow = (wm * 64 + (lane & 15)) * 32 + (lane >> 4) * 8;
  const int brow = (wn * 64 + (lane & 15)) * 32 + (lane >> 4) * 8;

  for (int kb = 0; kb < K; kb += 32) {
    bf16x8 a0 = *(const bf16x8*)(gA + kb);
    bf16x8 a1 = *(const bf16x8*)(gA + (size_t)64 * K + kb);
    bf16x8 b0 = *(const bf16x8*)(gB + kb);
    bf16x8 b1 = *(const bf16x8*)(gB + (size_t)64 * K + kb);
    __syncthreads();
    *(bf16x8*)&lsA[sr * 32 + sc]        = a0;
    *(bf16x8*)&lsA[(64 + sr) * 32 + sc] = a1;
    *(bf16x8*)&lsB[sr * 32 + sc]        = b0;
    *(bf16x8*)&lsB[(64 + sr) * 32 + sc] = b1;
    __syncthreads();
    bf16x8 af[4], bfv[4];
#pragma unroll
    for (int i = 0; i < 4; i++) af[i]  = *(const bf16x8*)&lsA[arow + i * 16 * 32];
#pragma unroll
    for (int j = 0; j < 4; j++) bfv[j] = *(const bf16x8*)&lsB[brow + j * 16 * 32];
#pragma unroll
    for (int i = 0; i < 4; i++)
#pragma unroll
      for (int j = 0; j < 4; j++)
        acc[i][j] = __builtin_amdgcn_mfma_f32_16x16x32_bf16(af[i], bfv[j], acc[i][j], 0, 0, 0);
  }

  const float s = (*sacc_p) * sinvn + sbias;
  const int r0 = bm * 128 + wm * 64 + (lane >> 4) * 4;
  const int c0 = bn * 128 + wn * 64 + (lane & 15);
#pragma unroll
  for (int i = 0; i < 4; i++) {
#pragma unroll
    for (int j = 0; j < 4; j++) {
      const int col = c0 + j * 16;
#pragma unroll
      for (int r = 0; r < 4; r++) {
        const int row = r0 + i * 16 + r;
        const float v = acc[i][j][r] * s;
        const size_t idx = (size_t)row * N + col;
        if (mode == EP_STORE) {
          outb[idx] = (bf16_t)v;
        } else if (mode == EP_BIAS_RES) {
          resid[idx] += v + bias[col];
        } else {  // EP_BIAS_GELU (exact gelu)
          const float t = v + bias[col];
          outb[idx] = (bf16_t)(0.5f * t * (1.0f + erff(t * 0.70710678118654752f)));
        }
      }
    }
  }
}

// ---------------- LayerNorm: one block per row; f32 gamma/beta; bf16 out -------------
template <typename TIN>
__global__ __launch_bounds__(256)
void ln_kern(const TIN* __restrict__ x, const float* __restrict__ g,
             const float* __restrict__ b, bf16_t* __restrict__ y, const int W)
{
  const int row = blockIdx.x;
  const int tid = threadIdx.x;
  const TIN* xr = x + (size_t)row * W;
  float s = 0.f, s2 = 0.f;
  for (int i = tid; i < W; i += 256) {
    const float v = (float)xr[i];
    s += v; s2 += v * v;
  }
#pragma unroll
  for (int off = 32; off > 0; off >>= 1) {
    s  += __shfl_xor(s,  off, 64);
    s2 += __shfl_xor(s2, off, 64);
  }
  __shared__ float red[8];
  if ((tid & 63) == 0) { red[(tid >> 6) * 2] = s; red[(tid >> 6) * 2 + 1] = s2; }
  __syncthreads();
  const float ts  = red[0] + red[2] + red[4] + red[6];
  const float ts2 = red[1] + red[3] + red[5] + red[7];
  const float invW = 1.0f / (float)W;
  const float mean = ts * invW;
  const float var  = fmaxf(ts2 * invW - mean * mean, 0.f);
  const float rs   = rsqrtf(var + 1e-5f);
  bf16_t* yr = y + (size_t)row * W;
  for (int i = tid; i < W; i += 256) {
    const float v = ((float)xr[i] - mean) * rs * g[i] + b[i];
    yr[i] = (bf16_t)v;
  }
}

// ---------------- MFMA flash attention ----------------
// grid (NSEQ/64, NH, NB), 256 threads = 4 waves. WG handles one (b,h) + 64 q rows;
// each wave owns 16 q rows. KV tiles of 64. 16x16x32 bf16 MFMA for QK^T and PV.
__global__ __launch_bounds__(256)
void attn_mfma(const bf16_t* __restrict__ qkv, bf16_t* __restrict__ o)
{
  __shared__ __align__(16) bf16_t Ks[64][72];      // K [kv][d], +8 pad
  __shared__ __align__(16) bf16_t Vt[64][72];      // V^T [d][kv], +8 pad
  __shared__ __align__(16) bf16_t Pw[4][16][72];   // per-wave P [q][kv], +8 pad
  const int tid  = threadIdx.x;
  const int lane = tid & 63;
  const int wave = tid >> 6;
  const int quad = lane >> 4;
  const int l15  = lane & 15;
  const int qb = blockIdx.x, hh = blockIdx.y, bb = blockIdx.z;
  const size_t tokbase = (size_t)bb * NSEQ;

  // Q A-fragments for this lane's q row: Q[qrow][kk*32 + quad*8 + j]
  const int qrow = qb * 64 + wave * 16 + l15;
  bf16x8 qf[2];
  {
    const bf16_t* qp = qkv + (tokbase + qrow) * QKVW + hh * DH;
    qf[0] = *(const bf16x8*)(qp + quad * 8);
    qf[1] = *(const bf16x8*)(qp + 32 + quad * 8);
  }

  f32x4 Ot[4];                       // O C-frags: col d = dt*16+l15, row q = quad*4+r
#pragma unroll
  for (int i = 0; i < 4; i++) Ot[i] = (f32x4){0.f, 0.f, 0.f, 0.f};
  float m_r[4], l_r[4];
#pragma unroll
  for (int r = 0; r < 4; r++) { m_r[r] = -1e30f; l_r[r] = 0.f; }

  // staging coords: thread -> kv row (tid&63), d-base (tid>>6)*16
  const int skv = tid & 63;
  const int sd  = (tid >> 6) * 16;

  for (int kt = 0; kt < NSEQ / 64; ++kt) {
    const bf16_t* kp = qkv + (tokbase + kt * 64 + skv) * QKVW + INNERV + hh * DH + sd;
    const bf16_t* vp = kp + INNERV;
    bf16x8 k0 = *(const bf16x8*)kp;
    bf16x8 k1 = *(const bf16x8*)(kp + 8);
    bf16x8 v0 = *(const bf16x8*)vp;
    bf16x8 v1 = *(const bf16x8*)(vp + 8);
    __syncthreads();                 // prev tile's LDS reads complete
    *(bf16x8*)&Ks[skv][sd]     = k0;
    *(bf16x8*)&Ks[skv][sd + 8] = k1;
#pragma unroll
    for (int e = 0; e < 8; e++) { Vt[sd + e][skv] = v0[e]; Vt[sd + 8 + e][skv] = v1[e]; }
    __syncthreads();

    // S = Q K^T : 4 col-tiles of 16 kv, 2 k-steps each
    f32x4 st[4];
#pragma unroll
    for (int nt = 0; nt < 4; nt++) {
      bf16x8 b0 = *(const bf16x8*)&Ks[nt * 16 + l15][quad * 8];
      bf16x8 b1 = *(const bf16x8*)&Ks[nt * 16 + l15][32 + quad * 8];
      f32x4 c = (f32x4){0.f, 0.f, 0.f, 0.f};
      c = __builtin_amdgcn_mfma_f32_16x16x32_bf16(qf[0], b0, c, 0, 0, 0);
      c = __builtin_amdgcn_mfma_f32_16x16x32_bf16(qf[1], b1, c, 0, 0, 0);
      st[nt] = c;
    }

    // online softmax; SCALE=0.125 folded here (S is f32)
    float rmax[4];
#pragma unroll
    for (int r = 0; r < 4; r++) {
      float v = fmaxf(fmaxf(st[0][r], st[1][r]), fmaxf(st[2][r], st[3][r]));
      v = fmaxf(v, __shfl_xor(v, 1, 64));
      v = fmaxf(v, __shfl_xor(v, 2, 64));
      v = fmaxf(v, __shfl_xor(v, 4, 64));
      v = fmaxf(v, __shfl_xor(v, 8, 64));
      rmax[r] = v * 0.125f;
    }
    float alpha[4];
#pragma unroll
    for (int r = 0; r < 4; r++) {
      const float mnew = fmaxf(m_r[r], rmax[r]);
      alpha[r] = __expf(m_r[r] - mnew);
      m_r[r] = mnew;
    }
    float rsum[4] = {0.f, 0.f, 0.f, 0.f};
#pragma unroll
    for (int nt = 0; nt < 4; nt++) {
#pragma unroll
      for (int r = 0; r < 4; r++) {
        const float p = __expf(st[nt][r] * 0.125f - m_r[r]);
        rsum[r] += p;
        Pw[wave][quad * 4 + r][nt * 16 + l15] = (bf16_t)p;
      }
    }
#pragma unroll
    for (int r = 0; r < 4; r++) {
      float v = rsum[r];
      v += __shfl_xor(v, 1, 64);
      v += __shfl_xor(v, 2, 64);
      v += __shfl_xor(v, 4, 64);
      v += __shfl_xor(v, 8, 64);
      l_r[r] = l_r[r] * alpha[r] + v;
    }
#pragma unroll
    for (int dt = 0; dt < 4; dt++)
#pragma unroll
      for (int r = 0; r < 4; r++) Ot[dt][r] *= alpha[r];

    __syncthreads();                 // Pw visible (wave-local slab, wg barrier is safe)

    // O += P V : A = P[q][kv], B = Vt[d][kv]
#pragma unroll
    for (int kk = 0; kk < 2; kk++) {
      bf16x8 pa = *(const bf16x8*)&Pw[wave][l15][kk * 32 + quad * 8];
#pragma unroll
      for (int dt = 0; dt < 4; dt++) {
        bf16x8 vb = *(const bf16x8*)&Vt[dt * 16 + l15][kk * 32 + quad * 8];
        Ot[dt] = __builtin_amdgcn_mfma_f32_16x16x32_bf16(pa, vb, Ot[dt], 0, 0, 0);
      }
    }
  }

  float inv[4];
#pragma unroll
  for (int r = 0; r < 4; r++) inv[r] = 1.0f / l_r[r];
#pragma unroll
  for (int dt = 0; dt < 4; dt++) {
#pragma unroll
    for (int r = 0; r < 4; r++) {
      const int q = qb * 64 + wave * 16 + quad * 4 + r;
      const int d = dt * 16 + l15;
      o[(tokbase + q) * INNERV + hh * DH + d] = (bf16_t)(Ot[dt][r] * inv[r]);
    }
  }
}

// ---------------- ternary quant helpers (f32 weights in) ----------------
__global__ __launch_bounds__(64)
void zero_kern(float* __restrict__ p)
{
  p[threadIdx.x] = 0.f;
}

__global__ __launch_bounds__(256)
void absmean_kern(const float* __restrict__ w, const long n, float* __restrict__ acc)
{
  const int tid = threadIdx.x;
  float s = 0.f;
  const size_t stride = (size_t)256 * gridDim.x * 4;
  for (size_t i = ((size_t)blockIdx.x * 256 + tid) * 4; i < (size_t)n; i += stride) {
    f32x4 t = *(const f32x4*)(w + i);
    s += fabsf(t[0]) + fabsf(t[1]) + fabsf(t[2]) + fabsf(t[3]);
  }
#pragma unroll
  for (int off = 32; off > 0; off >>= 1) s += __shfl_xor(s, off, 64);
  __shared__ float red[4];
  if ((tid & 63) == 0) red[tid >> 6] = s;
  __syncthreads();
  if (tid == 0) atomicAdd(acc, red[0] + red[1] + red[2] + red[3]);
}

// ternary: wq = clip(round(w/s), -1, 1) stored EXACTLY as bf16 {-1,0,1}; s applied in GEMM
__global__ __launch_bounds__(256)
void quant_kern(const float* __restrict__ w, bf16_t* __restrict__ wq,
                const int n, const float* __restrict__ acc, const float invn)
{
  const int i = blockIdx.x * 256 + threadIdx.x;
  if (i >= n) return;
  const float s = (*acc) * invn + 1e-8f;
  float q = rintf(w[i] / s);  // round-half-even, matches jnp.round
  q = fminf(1.f, fmaxf(-1.f, q));
  wq[i] = (bf16_t)q;
}

__global__ __launch_bounds__(256)
void copyf_kern(const float* __restrict__ in, float* __restrict__ out, const int n4)
{
  const int i = blockIdx.x * 256 + threadIdx.x;
  if (i < n4) ((f32x4*)out)[i] = ((const f32x4*)in)[i];
}

__global__ __launch_bounds__(256)
void f2b_kern(const float* __restrict__ in, bf16_t* __restrict__ out, const int n)
{
  const int i = blockIdx.x * 256 + threadIdx.x;
  if (i < n) out[i] = (bf16_t)in[i];
}

// ---------------- driver ----------------
extern "C" void kernel_launch(void* const* d_in, const int* in_sizes, int n_in,
                              void* d_out, int out_size, void* d_ws, size_t ws_size,
                              hipStream_t stream)
{
  // ALL inputs are float32 (per reference setup_inputs dtypes).
  const float* x     = (const float*)d_in[0];
  const float* ln1_g = (const float*)d_in[1];
  const float* ln1_b = (const float*)d_in[2];
  const float* Wqkv  = (const float*)d_in[3];
  const float* ln2_g = (const float*)d_in[4];
  const float* ln2_b = (const float*)d_in[5];
  const float* Wo    = (const float*)d_in[6];
  const float* bo    = (const float*)d_in[7];
  const float* fg1   = (const float*)d_in[8];
  const float* fb1   = (const float*)d_in[9];
  const float* W1    = (const float*)d_in[10];
  const float* b1    = (const float*)d_in[11];
  const float* fg2   = (const float*)d_in[12];
  const float* fb2   = (const float*)d_in[13];
  const float* W2    = (const float*)d_in[14];
  const float* b2    = (const float*)d_in[15];

  char* ws = (char*)d_ws;
  size_t off = 0;
  float*  sacc  = (float*)(ws + off);  off += 256;                         // scale sums; [63] stays 0
  float*  h     = (float*)(ws + off);  off += (size_t)TOKENS * DIMV * 4;   // 25.2 MB residual stream
  bf16_t* bigA  = (bf16_t*)(ws + off); off += (size_t)TOKENS * MLPW * 2;   // 50.3 MB LN outs / attn out
  bf16_t* bigB  = (bf16_t*)(ws + off); off += (size_t)TOKENS * MLPW * 2;   // 50.3 MB qkv / gelu out
  bf16_t* q_qkv = (bf16_t*)(ws + off); off += (size_t)QKVW * DIMV * 2;
  bf16_t* q_o   = (bf16_t*)(ws + off); off += (size_t)DIMV * INNERV * 2;
  bf16_t* q_1   = (bf16_t*)(ws + off); off += (size_t)MLPW * DIMV * 2;
  bf16_t* q_2   = (bf16_t*)(ws + off); off += (size_t)DIMV * MLPW * 2;     // total ~140 MB

  bf16_t* obuf   = bigA;                              // attn out (12.6 MB)
  bf16_t* ln2out = bigA + (size_t)TOKENS * INNERV;    // LN2 out

  zero_kern<<<1, 64, 0, stream>>>(sacc);
  copyf_kern<<<TOKENS * DIMV / 4 / 256, 256, 0, stream>>>(x, h, TOKENS * DIMV / 4);

  for (int lyr = 0; lyr < 6; ++lyr) {
    const float* wqkv_l = Wqkv + (size_t)lyr * QKVW * DIMV;
    const float* wo_l   = Wo   + (size_t)lyr * DIMV * INNERV;
    const float* w1_l   = W1   + (size_t)lyr * MLPW * DIMV;
    const float* w2_l   = W2   + (size_t)lyr * DIMV * MLPW;
    const float *sq, *so, *s1, *s2p;
    float iq, io, i1, i2, bq, bo2, bb1v, bb2v;
    if (lyr < 5) {
      absmean_kern<<<256, 256, 0, stream>>>(wqkv_l, (long)QKVW * DIMV, &sacc[lyr * 4 + 0]);
      absmean_kern<<<256, 256, 0, stream>>>(wo_l,   (long)DIMV * INNERV, &sacc[lyr * 4 + 1]);
      absmean_kern<<<256, 256, 0, stream>>>(w1_l,   (long)MLPW * DIMV, &sacc[lyr * 4 + 2]);
      absmean_kern<<<256, 256, 0, stream>>>(w2_l,   (long)DIMV * MLPW, &sacc[lyr * 4 + 3]);
      quant_kern<<<QKVW * DIMV / 256, 256, 0, stream>>>(wqkv_l, q_qkv, QKVW * DIMV, &sacc[lyr * 4 + 0], 1.0f / (QKVW * DIMV));
      quant_kern<<<DIMV * INNERV / 256, 256, 0, stream>>>(wo_l, q_o, DIMV * INNERV, &sacc[lyr * 4 + 1], 1.0f / (DIMV * INNERV));
      quant_kern<<<MLPW * DIMV / 256, 256, 0, stream>>>(w1_l, q_1, MLPW * DIMV, &sacc[lyr * 4 + 2], 1.0f / (MLPW * DIMV));
      quant_kern<<<DIMV * MLPW / 256, 256, 0, stream>>>(w2_l, q_2, DIMV * MLPW, &sacc[lyr * 4 + 3], 1.0f / (DIMV * MLPW));
      sq = &sacc[lyr * 4 + 0]; iq = 1.0f / (QKVW * DIMV); bq = 1e-8f;
      so = &sacc[lyr * 4 + 1]; io = 1.0f / (DIMV * INNERV); bo2 = 1e-8f;
      s1 = &sacc[lyr * 4 + 2]; i1 = 1.0f / (MLPW * DIMV); bb1v = 1e-8f;
      s2p = &sacc[lyr * 4 + 3]; i2 = 1.0f / (DIMV * MLPW); bb2v = 1e-8f;
    } else {
      // last layer: plain weights, bf16-cast, scale 1.0
      f2b_kern<<<QKVW * DIMV / 256, 256, 0, stream>>>(wqkv_l, q_qkv, QKVW * DIMV);
      f2b_kern<<<DIMV * INNERV / 256, 256, 0, stream>>>(wo_l, q_o, DIMV * INNERV);
      f2b_kern<<<MLPW * DIMV / 256, 256, 0, stream>>>(w1_l, q_1, MLPW * DIMV);
      f2b_kern<<<DIMV * MLPW / 256, 256, 0, stream>>>(w2_l, q_2, DIMV * MLPW);
      sq = so = s1 = s2p = &sacc[63];  // contains 0
      iq = io = i1 = i2 = 0.f;
      bq = bo2 = bb1v = bb2v = 1.0f;   // s = 0*0 + 1 = 1
    }

    // attention sub-block
    ln_kern<float><<<TOKENS, 256, 0, stream>>>(h, ln1_g + lyr * DIMV, ln1_b + lyr * DIMV, bigA, DIMV);
    gemm_nt<<<dim3(64, QKVW / 128), 256, 0, stream>>>(bigA, q_qkv, DIMV, QKVW, EP_STORE, sq, iq, bq, nullptr, nullptr, bigB);
    attn_mfma<<<dim3(NSEQ / 64, NH, NB), 256, 0, stream>>>(bigB, obuf);
    ln_kern<bf16_t><<<TOKENS, 256, 0, stream>>>(obuf, ln2_g + lyr * INNERV, ln2_b + lyr * INNERV, ln2out, INNERV);
    gemm_nt<<<dim3(64, DIMV / 128), 256, 0, stream>>>(ln2out, q_o, INNERV, DIMV, EP_BIAS_RES, so, io, bo2, bo + lyr * DIMV, h, nullptr);
    // FF sub-block
    ln_kern<float><<<TOKENS, 256, 0, stream>>>(h, fg1 + lyr * DIMV, fb1 + lyr * DIMV, bigA, DIMV);
    gemm_nt<<<dim3(64, MLPW / 128), 256, 0, stream>>>(bigA, q_1, DIMV, MLPW, EP_BIAS_GELU, s1, i1, bb1v, b1 + lyr * MLPW, nullptr, bigB);
    ln_kern<bf16_t><<<TOKENS, 256, 0, stream>>>(bigB, fg2 + lyr * MLPW, fb2 + lyr * MLPW, bigA, MLPW);
    gemm_nt<<<dim3(64, DIMV / 128), 256, 0, stream>>>(bigA, q_2, MLPW, DIMV, EP_BIAS_RES, s2p, i2, bb2v, b2 + lyr * DIMV, h, nullptr);
  }

  // OUTPUT IS FLOAT32 (reference returns f32) — copy residual stream directly.
  copyf_kern<<<TOKENS * DIMV / 4 / 256, 256, 0, stream>>>(h, (float*)d_out, TOKENS * DIMV / 4);
}